// Round 13
// baseline (378.439 us; speedup 1.0000x reference)
//
#include <hip/hip_runtime.h>

// LSTMP via MFMA, fp32 I/O, f16 compute, fp32 accumulate.
// B=4096, T=512, IN=4, HID=64, PROJ=52.
//
// Round-13 = Round-12 machine at TWO BLOCKS PER CU (clean occupancy-2 retest).
// 512 blocks x 256 thr, 8 batches/block, launch_bounds(256,2). R6's earlier
// occupancy-2 failure was confounded: it still had in-loop GLOBAL x loads, so
// every barrier dragged an s_waitcnt vmcnt(0) HBM drain. Here (R9 fix) x is
// staged to LDS once; the loop is LDS-only. The SIMD-partner wave (other
// block, independent barrier) fills this wave's stall gaps (post-barrier
// ds_read ~120 cyc, MFMA drain, trans chain tails) -- phase-independent TLP.
//  - folded projection: gates = (Whh@Whr)@d + [Wih|b]@[x;1], M precomputed.
//  - rotation: xb-MFMA for t+1 issued pre-barrier, carried in accumulators.
//  - duplicate-batch trick (R10, verified): gate B-frag col c reads d row c&7
//    -> C cols 8-15 duplicate batch c-8; lane col>=8 owns C rows {2,3}.
//    Exact 2 units/lane, 20 trans/wave, 40/SIMD (floor unchanged), 0 bpermute.
//  - ONE lgkm-only barrier/step; d rows 0-7 double-buffered (136B stride).
// log2e folded (i,f,o xL; g x2L; c'=2L*c); RTNE f16 d.
// Per-unit arithmetic identical to R12 -> absmax exactly 9.765625e-4.

#define T_STEPS 512
#define HID 64
#define NPROJ 52
#define NBATCH 8
#define ROWB 136
#define DBYTES (NBATCH * ROWB)     // 1088 B per d buffer
#define XBYTES (T_STEPS * 64)      // 32768 B: x_lds[t][b] 8B cells (4 x f16)
#define LOG2E 1.44269504088896340736f

typedef _Float16 half8 __attribute__((ext_vector_type(8)));
typedef float f32x4 __attribute__((ext_vector_type(4)));

__device__ __forceinline__ float exp2_f(float x) {
#if __has_builtin(__builtin_amdgcn_exp2f)
    return __builtin_amdgcn_exp2f(x);
#else
    return exp2f(x);
#endif
}
__device__ __forceinline__ float rcp_f(float x) {
    return __builtin_amdgcn_rcpf(x);
}

__global__ __launch_bounds__(256, 2)
void lstmp_kernel(const float* __restrict__ x,      // [4096][512][4]
                  const float* __restrict__ Wih,    // [256][4]
                  const float* __restrict__ Whh,    // [256][52]
                  const float* __restrict__ bih,    // [256]
                  const float* __restrict__ bhh,    // [256]
                  const float* __restrict__ Whr,    // [52][64]
                  float* __restrict__ out)          // [4096][52]
{
    __shared__ char lds[XBYTES + 2 * DBYTES];
    char* xl = lds;                 // x_lds: [t][b] 8B cells
    char* dl = lds + XBYTES;        // double-buffered d, [8 batch][136B]

    const int lane = threadIdx.x & 63;
    const int wave = threadIdx.x >> 6;   // 0..3
    const int quad = lane >> 4;
    const int col  = lane & 15;
    const bool low = col < 8;            // duplicate-batch trick: col>=8 mirrors col-8
    const int bloc = col & 7;            // batch within block

    // ---- zero d buffers (t=0 reads buffer 0 as d(-1)=0) ----
    {
        unsigned* p = (unsigned*)dl;
        for (int i = threadIdx.x; i < (int)(2 * DBYTES / 4); i += 256) p[i] = 0u;
    }

    // ---- stage x -> LDS as f16 (one-time; coalesced global reads) ----
    {
        const float4* xg = (const float4*)x + (size_t)blockIdx.x * NBATCH * T_STEPS;
        for (int i = threadIdx.x; i < NBATCH * T_STEPS; i += 256) {
            const int b = i >> 9;          // global layout is b-major
            const int t = i & (T_STEPS - 1);
            const float4 v = xg[i];
            union { _Float16 h[4]; unsigned long long q; } u;
            u.h[0] = (_Float16)v.x; u.h[1] = (_Float16)v.y;
            u.h[2] = (_Float16)v.z; u.h[3] = (_Float16)v.w;
            *(unsigned long long*)(xl + t * 64 + b * 8) = u.q;
        }
    }

    // ---- one-time: M = Whh @ Whr for this wave's 4 gate tiles (fp32) ----
    const int hid = wave * 16 + col;
    float macc[4][16];
#pragma unroll
    for (int g = 0; g < 4; ++g)
#pragma unroll
        for (int kk = 0; kk < 16; ++kk) macc[g][kk] = 0.0f;

    for (int p = 0; p < NPROJ; ++p) {
        float wv[4];
#pragma unroll
        for (int g = 0; g < 4; ++g) wv[g] = Whh[(g * HID + hid) * NPROJ + p];
        const float* wr = Whr + p * HID + quad * 8;
        const float4 r0 = *(const float4*)(wr);
        const float4 r1 = *(const float4*)(wr + 4);
        const float4 r2 = *(const float4*)(wr + 32);
        const float4 r3 = *(const float4*)(wr + 36);
        const float rk[16] = {r0.x, r0.y, r0.z, r0.w, r1.x, r1.y, r1.z, r1.w,
                              r2.x, r2.y, r2.z, r2.w, r3.x, r3.y, r3.z, r3.w};
#pragma unroll
        for (int g = 0; g < 4; ++g)
#pragma unroll
            for (int kk = 0; kk < 16; ++kk) macc[g][kk] = fmaf(wv[g], rk[kk], macc[g][kk]);
    }

    // ---- fold log2e, convert to f16 A-frags ----
    half8 aM[4][2];    // M-part, K=64
    half8 aXB[4];      // [Wih | bias] part, K=32 (quad0: k<4 = x, k==4 = 1-col)
#pragma unroll
    for (int g = 0; g < 4; ++g) {
        const float scale = (g == 2) ? (2.0f * LOG2E) : LOG2E;
#pragma unroll
        for (int ch = 0; ch < 2; ++ch)
#pragma unroll
            for (int j = 0; j < 8; ++j)
                aM[g][ch][j] = (_Float16)(macc[g][ch * 8 + j] * scale);
        const int row = g * HID + hid;
#pragma unroll
        for (int j = 0; j < 8; ++j) {
            const int k = quad * 8 + j;
            float v = 0.0f;
            if (k < 4)       v = Wih[row * 4 + k];
            else if (k == 4) v = bih[row] + bhh[row];
            aXB[g][j] = (_Float16)(v * scale);
        }
    }

    float cacc[2] = {0.0f, 0.0f};   // c' = 2L*c for hid = 16w + quad*4 + (low?0:2) + u

    // d write: this lane's 2 units (f16 pair = b32) at row bloc
    const int dwoff  = bloc * ROWB + (16 * wave + quad * 4 + (low ? 0 : 2)) * 2;
    const int drbase = bloc * ROWB + quad * 16;   // d B-frag read base (+ch*64)
    const char* xrd  = xl + bloc * 8;             // + t*64 per step

    __syncthreads();   // staging + zeros visible

    // ---- pre-seed accumulators with xb contribution for t=0 ----
    f32x4 ai, af_, ag_, ao_;
    {
        half8 bx;
#pragma unroll
        for (int j = 0; j < 8; ++j) bx[j] = (_Float16)0.0f;
        if (quad == 0) {
            union { unsigned long long q; _Float16 h[4]; } u;
            u.q = *(const unsigned long long*)(xrd + 0 * 64);
            bx[0] = u.h[0]; bx[1] = u.h[1]; bx[2] = u.h[2]; bx[3] = u.h[3];
            bx[4] = (_Float16)1.0f;
        }
        const f32x4 z = {0.f, 0.f, 0.f, 0.f};
        ai  = __builtin_amdgcn_mfma_f32_16x16x32_f16(aXB[0], bx, z, 0, 0, 0);
        af_ = __builtin_amdgcn_mfma_f32_16x16x32_f16(aXB[1], bx, z, 0, 0, 0);
        ag_ = __builtin_amdgcn_mfma_f32_16x16x32_f16(aXB[2], bx, z, 0, 0, 0);
        ao_ = __builtin_amdgcn_mfma_f32_16x16x32_f16(aXB[3], bx, z, 0, 0, 0);
    }

#pragma unroll 1
    for (int t = 0; t < T_STEPS; ++t) {
        const char* rbuf = dl + (t & 1) * DBYTES;
        char* wbuf = dl + ((t + 1) & 1) * DBYTES;

        // ---- post-barrier critical path: d(t-1) B-frags, then 8 M-MFMA ----
        half8 bd0, bd1;
        {
            const char* p0 = rbuf + drbase;
            union { unsigned long long q[2]; half8 h; } u0, u1;
            u0.q[0] = *(const unsigned long long*)(p0);
            u0.q[1] = *(const unsigned long long*)(p0 + 8);
            u1.q[0] = *(const unsigned long long*)(p0 + 64);
            u1.q[1] = *(const unsigned long long*)(p0 + 72);
            bd0 = u0.h; bd1 = u1.h;
        }
        ai  = __builtin_amdgcn_mfma_f32_16x16x32_f16(aM[0][0], bd0, ai,  0, 0, 0);
        af_ = __builtin_amdgcn_mfma_f32_16x16x32_f16(aM[1][0], bd0, af_, 0, 0, 0);
        ag_ = __builtin_amdgcn_mfma_f32_16x16x32_f16(aM[2][0], bd0, ag_, 0, 0, 0);
        ao_ = __builtin_amdgcn_mfma_f32_16x16x32_f16(aM[3][0], bd0, ao_, 0, 0, 0);
        ai  = __builtin_amdgcn_mfma_f32_16x16x32_f16(aM[0][1], bd1, ai,  0, 0, 0);
        af_ = __builtin_amdgcn_mfma_f32_16x16x32_f16(aM[1][1], bd1, af_, 0, 0, 0);
        ag_ = __builtin_amdgcn_mfma_f32_16x16x32_f16(aM[2][1], bd1, ag_, 0, 0, 0);
        ao_ = __builtin_amdgcn_mfma_f32_16x16x32_f16(aM[3][1], bd1, ao_, 0, 0, 0);

        // ---- activations for this lane's 2 units (20 trans/wave) ----
        union { _Float16 h[2]; unsigned w; } du;
#pragma unroll
        for (int u = 0; u < 2; ++u) {
            const int r = (low ? 0 : 2) + u;
            const float iv = rcp_f(1.0f + exp2_f(-ai[r]));                       // sigmoid
            const float fv = rcp_f(1.0f + exp2_f(-af_[r]));
            const float ov = rcp_f(1.0f + exp2_f(-ao_[r]));
            const float gs = fmaf(-4.0f * LOG2E, rcp_f(1.0f + exp2_f(ag_[r])),
                                  2.0f * LOG2E);                                 // 2L*tanh(g)
            const float cn = fmaf(fv, cacc[u], iv * gs);                         // c' = 2L*c
            cacc[u] = cn;
            const float th = fmaf(-2.0f, rcp_f(1.0f + exp2_f(cn)), 1.0f);        // tanh(c)
            du.h[u] = (_Float16)(ov * th);                                       // RTNE
        }
        *(unsigned*)(wbuf + dwoff) = du.w;

        // ---- pre-barrier: xb-MFMA for step t+1 (independent of d(t)) ----
        {
            const int tn = (t + 1 < T_STEPS) ? (t + 1) : (T_STEPS - 1);
            half8 bx;
#pragma unroll
            for (int j = 0; j < 8; ++j) bx[j] = (_Float16)0.0f;
            if (quad == 0) {
                union { unsigned long long q; _Float16 h[4]; } u;
                u.q = *(const unsigned long long*)(xrd + tn * 64);
                bx[0] = u.h[0]; bx[1] = u.h[1]; bx[2] = u.h[2]; bx[3] = u.h[3];
                bx[4] = (_Float16)1.0f;
            }
            const f32x4 z = {0.f, 0.f, 0.f, 0.f};
            ai  = __builtin_amdgcn_mfma_f32_16x16x32_f16(aXB[0], bx, z, 0, 0, 0);
            af_ = __builtin_amdgcn_mfma_f32_16x16x32_f16(aXB[1], bx, z, 0, 0, 0);
            ag_ = __builtin_amdgcn_mfma_f32_16x16x32_f16(aXB[2], bx, z, 0, 0, 0);
            ao_ = __builtin_amdgcn_mfma_f32_16x16x32_f16(aXB[3], bx, z, 0, 0, 0);
        }

        __syncthreads();   // the ONLY barrier per step (lgkm-only drain)
    }

    // ---- epilogue: h_T = Whr @ d(511); d(511) is in buffer 0 ----
    half8 aP[2];
    const int prow = wave * 16 + col;
#pragma unroll
    for (int ch = 0; ch < 2; ++ch)
#pragma unroll
        for (int j = 0; j < 8; ++j) {
            const int k = ch * 32 + quad * 8 + j;
            aP[ch][j] = (_Float16)((prow < NPROJ) ? Whr[prow * HID + k] : 0.0f);
        }

    half8 bd0, bd1;
    {
        const char* p0 = dl + 0 * DBYTES + drbase;
        union { unsigned long long q[2]; half8 h; } u0, u1;
        u0.q[0] = *(const unsigned long long*)(p0);
        u0.q[1] = *(const unsigned long long*)(p0 + 8);
        u1.q[0] = *(const unsigned long long*)(p0 + 64);
        u1.q[1] = *(const unsigned long long*)(p0 + 72);
        bd0 = u0.h; bd1 = u1.h;
    }
    f32x4 hf = {0.f, 0.f, 0.f, 0.f};
    hf = __builtin_amdgcn_mfma_f32_16x16x32_f16(aP[0], bd0, hf, 0, 0, 0);
    hf = __builtin_amdgcn_mfma_f32_16x16x32_f16(aP[1], bd1, hf, 0, 0, 0);

    // store: p = wave*16 + quad*4 + r, batch = blockIdx*8 + col (cols 0-7 only)
    if (low) {
        const size_t bg = (size_t)blockIdx.x * NBATCH + col;
        float* o = out + bg * NPROJ;
        const int p0 = wave * 16 + quad * 4;
#pragma unroll
        for (int r = 0; r < 4; ++r) {
            const int p = p0 + r;
            if (p < NPROJ) o[p] = hf[r];
        }
    }
}

extern "C" void kernel_launch(void* const* d_in, const int* in_sizes, int n_in,
                              void* d_out, int out_size, void* d_ws, size_t ws_size,
                              hipStream_t stream) {
    const float* x   = (const float*)d_in[0];
    const float* Wih = (const float*)d_in[1];
    const float* Whh = (const float*)d_in[2];
    const float* bih = (const float*)d_in[3];
    const float* bhh = (const float*)d_in[4];
    const float* Whr = (const float*)d_in[5];
    float* out = (float*)d_out;

    dim3 grid(4096 / NBATCH);   // 512 blocks -> 2 independent blocks per CU
    dim3 block(256);            // 4 waves; 2 waves/SIMD across the two blocks
    lstmp_kernel<<<grid, block, 0, stream>>>(x, Wih, Whh, bih, bhh, Whr, out);
}